// Round 3
// baseline (161.011 us; speedup 1.0000x reference)
//
#include <hip/hip_runtime.h>

#define D_MODEL 1024
#define TPB_TOKENS 16   // tokens per block, GRID-STRIDED (dense moving front)

typedef float vfloat4 __attribute__((ext_vector_type(4)));

// ---------------------------------------------------------------------------
// out[tok][d] = t^2 * A[d] + t * B[d] + C[d]   (t = float(N_tokens[tok]))
//   A[d] = W[d,0]+W[d,3]+W[d,6]+W[d,9]
//   B[d] = W[d,1]+W[d,2]+2W[d,4]+2W[d,8]+2W[d,10]
//   C[d] = W[d,2]+2W[d,4]-W[d,5]+W[d,8]+W[d,10]+bias[d]
//
// R3 changes (R1 prologue-hoist and R2 store-flag were both null):
//  1. OCCUPANCY: fold W on the fly (no wv[48] array), 16-token value list,
//     target <64 VGPR + __launch_bounds__(256,8) -> 8 waves/SIMD = 32
//     waves/CU, 2x the outstanding-store depth of the ~100-VGPR R2 build.
//     (The 6.6 TB/s harness fill runs at 8 VGPR / max occupancy.)
//  2. WRITE FRONT: grid-stride token order tok = blockIdx.x + k*gridDim.x.
//     Adjacent blocks write adjacent 4 KiB rows and k sweeps one dense
//     contiguous front across the 134 MB output — the same pattern as the
//     6.6 TB/s fill — instead of 1024 scattered fronts 128 KiB apart.
// ---------------------------------------------------------------------------
__global__ __launch_bounds__(256, 8) void n2_embed_kernel(
    const int* __restrict__ toks,
    const float* __restrict__ W,
    const float* __restrict__ bias,
    float* __restrict__ out,
    int n_tokens,
    int stride)                       // = gridDim.x
{
    const int d0 = threadIdx.x * 4;   // 256 threads cover D_MODEL = 1024

    const vfloat4 bb = *(const vfloat4*)(bias + d0);

    // Fold W rows into A/B/C immediately; 3 x float4 per row, rows are
    // 48 B each so every row is 16B-aligned. Transients die after each j.
    float A[4], B[4], C[4];
#pragma unroll
    for (int j = 0; j < 4; ++j) {
        const vfloat4* wp = (const vfloat4*)(W + (size_t)(d0 + j) * 12);
        vfloat4 wa = wp[0], wb = wp[1], wc = wp[2];
        float w0 = wa.x, w1 = wa.y, w2 = wa.z, w3 = wa.w;
        float w4 = wb.x, w5 = wb.y, w6 = wb.z;
        float w8 = wc.x, w9 = wc.y, w10 = wc.z;
        // Same FP ordering as the verified baseline (bit-identical output).
        A[j] = (w0 + w3) + (w6 + w9);
        B[j] = w1 + w2 + 2.0f * w4 + 2.0f * w8 + 2.0f * w10;
        C[j] = w2 + 2.0f * w4 - w5 + w8 + w10 + bb[j];
    }

    const int b = blockIdx.x;

    // Token values: block-uniform indices -> scalar loads, all issued up
    // front (guarded so the compiler may hoist them above the store loop).
    float tv[TPB_TOKENS];
#pragma unroll
    for (int k = 0; k < TPB_TOKENS; ++k) {
        int tok = b + k * stride;
        tv[k] = (tok < n_tokens) ? (float)toks[tok] : 0.0f;
    }

#pragma unroll
    for (int k = 0; k < TPB_TOKENS; ++k) {
        int tok = b + k * stride;
        if (tok >= n_tokens) continue;
        float t = tv[k];
        float t2 = t * t;
        vfloat4 o;
        o.x = fmaf(t2, A[0], fmaf(t, B[0], C[0]));
        o.y = fmaf(t2, A[1], fmaf(t, B[1], C[1]));
        o.z = fmaf(t2, A[2], fmaf(t, B[2], C[2]));
        o.w = fmaf(t2, A[3], fmaf(t, B[3], C[3]));
        // Plain 16B store: wave writes 1 KiB contiguous, the 4 waves of a
        // block cover one 4 KiB token row, adjacent blocks cover adjacent
        // rows -> dense moving front.
        *(vfloat4*)(out + (size_t)tok * D_MODEL + d0) = o;
    }
}

extern "C" void kernel_launch(void* const* d_in, const int* in_sizes, int n_in,
                              void* d_out, int out_size, void* d_ws, size_t ws_size,
                              hipStream_t stream) {
    const int* toks = (const int*)d_in[0];       // N_tokens [4,8192] (int32 view)
    const float* W = (const float*)d_in[1];      // [1024,12]
    const float* bias = (const float*)d_in[2];   // [1024]
    float* out = (float*)d_out;                  // [4,8192,1024] fp32

    int n_tokens = out_size / D_MODEL;           // 32768
    int blocks = (n_tokens + TPB_TOKENS - 1) / TPB_TOKENS;  // 2048

    n2_embed_kernel<<<blocks, 256, 0, stream>>>(toks, W, bias, out,
                                                n_tokens, blocks);
}